// Round 1
// baseline (215.405 us; speedup 1.0000x reference)
//
#include <hip/hip_runtime.h>

// Problem constants: B=8, L=64, D=768, H=12, d=64
#define DMODEL 768
#define NHEADS 12
#define RTOT   512           // B*L rows
#define BIW    9216          // NHEADS*DMODEL (per-(b,i) u/w row)

// ---------------------------------------------------------------------------
// Tiled linear: dst[r, cb*64+c] = (sum_m src[r, cb*src_col_mult + m] * W[m, cb*64+c] + bias[cb*64+c]) * scale
// grid = (16 row-tiles of 32, 12 col-tiles of 64), 256 threads
// ---------------------------------------------------------------------------
__global__ __launch_bounds__(256) void linear_tile(
    const float* __restrict__ src, int src_row_stride, int src_col_mult,
    const float* __restrict__ W, const float* __restrict__ bias,
    float* __restrict__ dst, int dst_row_stride, float scale)
{
    __shared__ float tile[32][DMODEL];   // 96 KB
    const int rt = blockIdx.x;
    const int cb = blockIdx.y;
    const int t  = threadIdx.x;
    const int colbase = cb * 64;
    const int scb = cb * src_col_mult;

    // stage 32x768 fp32 tile, coalesced float4
    #pragma unroll
    for (int kk = 0; kk < 24; ++kk) {
        int idx = t * 4 + kk * 1024;
        int r = idx / DMODEL, m = idx % DMODEL;
        *reinterpret_cast<float4*>(&tile[r][m]) =
            *reinterpret_cast<const float4*>(src + (size_t)(rt * 32 + r) * src_row_stride + scb + m);
    }
    __syncthreads();

    const int c = colbase + (t & 31) * 2;   // 2 output cols per thread
    const int g = t >> 5;                   // 8 groups x 4 rows
    float a0x = 0.f, a0y = 0.f, a1x = 0.f, a1y = 0.f;
    float a2x = 0.f, a2y = 0.f, a3x = 0.f, a3y = 0.f;

    for (int m = 0; m < DMODEL; m += 4) {
        float2 w0 = *reinterpret_cast<const float2*>(W + (size_t)(m + 0) * DMODEL + c);
        float2 w1 = *reinterpret_cast<const float2*>(W + (size_t)(m + 1) * DMODEL + c);
        float2 w2 = *reinterpret_cast<const float2*>(W + (size_t)(m + 2) * DMODEL + c);
        float2 w3 = *reinterpret_cast<const float2*>(W + (size_t)(m + 3) * DMODEL + c);
        float4 r0 = *reinterpret_cast<const float4*>(&tile[g * 4 + 0][m]);
        float4 r1 = *reinterpret_cast<const float4*>(&tile[g * 4 + 1][m]);
        float4 r2 = *reinterpret_cast<const float4*>(&tile[g * 4 + 2][m]);
        float4 r3 = *reinterpret_cast<const float4*>(&tile[g * 4 + 3][m]);
        a0x += r0.x * w0.x + r0.y * w1.x + r0.z * w2.x + r0.w * w3.x;
        a0y += r0.x * w0.y + r0.y * w1.y + r0.z * w2.y + r0.w * w3.y;
        a1x += r1.x * w0.x + r1.y * w1.x + r1.z * w2.x + r1.w * w3.x;
        a1y += r1.x * w0.y + r1.y * w1.y + r1.z * w2.y + r1.w * w3.y;
        a2x += r2.x * w0.x + r2.y * w1.x + r2.z * w2.x + r2.w * w3.x;
        a2y += r2.x * w0.y + r2.y * w1.y + r2.z * w2.y + r2.w * w3.y;
        a3x += r3.x * w0.x + r3.y * w1.x + r3.z * w2.x + r3.w * w3.x;
        a3y += r3.x * w0.y + r3.y * w1.y + r3.z * w2.y + r3.w * w3.y;
    }

    const float b0 = bias[c], b1 = bias[c + 1];
    const size_t rbase = (size_t)(rt * 32 + g * 4);
    float2 o;
    o.x = (a0x + b0) * scale; o.y = (a0y + b1) * scale;
    *reinterpret_cast<float2*>(dst + (rbase + 0) * dst_row_stride + c) = o;
    o.x = (a1x + b0) * scale; o.y = (a1y + b1) * scale;
    *reinterpret_cast<float2*>(dst + (rbase + 1) * dst_row_stride + c) = o;
    o.x = (a2x + b0) * scale; o.y = (a2y + b1) * scale;
    *reinterpret_cast<float2*>(dst + (rbase + 2) * dst_row_stride + c) = o;
    o.x = (a3x + b0) * scale; o.y = (a3y + b1) * scale;
    *reinterpret_cast<float2*>(dst + (rbase + 3) * dst_row_stride + c) = o;
}

// ---------------------------------------------------------------------------
// u[r,h,m] = sum_d Wk[m, h*64+d] * Qp[r, h*64+d];  c[r,h] = sum_d bk[h*64+d]*Qp[r,h*64+d]
// grid = (32 row-tiles of 16, 12 heads), 256 threads
// ---------------------------------------------------------------------------
__global__ __launch_bounds__(256) void qk_prep(
    const float* __restrict__ qp, const float* __restrict__ Wk, const float* __restrict__ bk,
    float* __restrict__ u, float* __restrict__ cvec)
{
    __shared__ float q[16][64];          // 4 KB
    const int rt = blockIdx.x, h = blockIdx.y, t = threadIdx.x;

    {   // stage 16x64 head-slice of Qp
        int idx = t * 4;
        int r = idx >> 6, d = idx & 63;
        *reinterpret_cast<float4*>(&q[r][d]) =
            *reinterpret_cast<const float4*>(qp + (size_t)(rt * 16 + r) * DMODEL + h * 64 + d);
    }
    __syncthreads();

    float acc[3][16];
    #pragma unroll
    for (int mm = 0; mm < 3; ++mm)
        #pragma unroll
        for (int r = 0; r < 16; ++r) acc[mm][r] = 0.f;

    for (int d4 = 0; d4 < 16; ++d4) {
        float4 wk[3];
        #pragma unroll
        for (int mm = 0; mm < 3; ++mm)
            wk[mm] = *reinterpret_cast<const float4*>(Wk + (size_t)(t + mm * 256) * DMODEL + h * 64 + d4 * 4);
        #pragma unroll
        for (int r = 0; r < 16; ++r) {
            float4 qq = *reinterpret_cast<const float4*>(&q[r][d4 * 4]);
            #pragma unroll
            for (int mm = 0; mm < 3; ++mm)
                acc[mm][r] += wk[mm].x * qq.x + wk[mm].y * qq.y + wk[mm].z * qq.z + wk[mm].w * qq.w;
        }
    }

    #pragma unroll
    for (int mm = 0; mm < 3; ++mm)
        #pragma unroll
        for (int r = 0; r < 16; ++r)
            u[(size_t)(rt * 16 + r) * BIW + h * DMODEL + t + mm * 256] = acc[mm][r];

    if (t < 16) {
        float s = 0.f;
        for (int d = 0; d < 64; ++d) s += bk[h * 64 + d] * q[t][d];
        cvec[(rt * 16 + t) * NHEADS + h] = s;
    }
}

// ---------------------------------------------------------------------------
// Core: per (b,i) block. scores -> softmax -> w = attn^T * value
// grid = 512, 256 threads
// ---------------------------------------------------------------------------
__global__ __launch_bounds__(256) void attn_core(
    const float* __restrict__ key, const float* __restrict__ value, const float* __restrict__ mask,
    const float* __restrict__ u, const float* __restrict__ cvec, float* __restrict__ w)
{
    __shared__ float u_lds[NHEADS][DMODEL];   // 36 KB
    __shared__ float part[8][NHEADS][64];     // 24 KB
    __shared__ float scores[NHEADS][64];      // 3 KB
    __shared__ float attn_t[64][16];          // 4 KB (cols 0..11 used)

    const int bi = blockIdx.x;
    const int t  = threadIdx.x;
    const size_t kvbase = (size_t)bi * 64 * DMODEL;

    // stage u[b,i] (36 KB) coalesced
    #pragma unroll
    for (int kk = 0; kk < 9; ++kk) {
        int idx = (t + kk * 256) * 4;
        *reinterpret_cast<float4*>(reinterpret_cast<float*>(u_lds) + idx) =
            *reinterpret_cast<const float4*>(u + (size_t)bi * BIW + idx);
    }
    __syncthreads();

    // ---- phase 1: partial scores. thread: j in {jl, jl+32}, m in [mc*96, mc*96+96)
    {
        const int jl = t & 31, mc = t >> 5;
        float acc0[NHEADS], acc1[NHEADS];
        #pragma unroll
        for (int h = 0; h < NHEADS; ++h) { acc0[h] = 0.f; acc1[h] = 0.f; }
        const float* k0 = key + kvbase + (size_t)jl * DMODEL + mc * 96;
        const float* k1 = k0 + 32 * DMODEL;
        #pragma unroll 4
        for (int mi = 0; mi < 24; ++mi) {
            float4 ka = *reinterpret_cast<const float4*>(k0 + mi * 4);
            float4 kb = *reinterpret_cast<const float4*>(k1 + mi * 4);
            const int m = mc * 96 + mi * 4;
            #pragma unroll
            for (int h = 0; h < NHEADS; ++h) {
                float4 uu = *reinterpret_cast<const float4*>(&u_lds[h][m]);
                acc0[h] += ka.x * uu.x + ka.y * uu.y + ka.z * uu.z + ka.w * uu.w;
                acc1[h] += kb.x * uu.x + kb.y * uu.y + kb.z * uu.z + kb.w * uu.w;
            }
        }
        #pragma unroll
        for (int h = 0; h < NHEADS; ++h) {
            part[mc][h][jl]      = acc0[h];
            part[mc][h][jl + 32] = acc1[h];
        }
    }
    __syncthreads();

    // ---- reduce partials + bias-dot + mask
    for (int p = t; p < NHEADS * 64; p += 256) {
        int h = p >> 6, j = p & 63;
        float s = 0.f;
        #pragma unroll
        for (int mc = 0; mc < 8; ++mc) s += part[mc][h][j];
        s += cvec[bi * NHEADS + h];
        s *= mask[bi * 64 + j];
        scores[h][j] = s;
    }
    __syncthreads();

    // ---- softmax over j per head: wave wv handles h = wv, wv+4, wv+8
    {
        const int wv = t >> 6, l = t & 63;
        #pragma unroll
        for (int hh = 0; hh < 3; ++hh) {
            const int h = wv + hh * 4;
            float s = scores[h][l];
            float mx = s;
            #pragma unroll
            for (int o = 1; o < 64; o <<= 1) mx = fmaxf(mx, __shfl_xor(mx, o));
            float e = __expf(s - mx);
            float sm = e;
            #pragma unroll
            for (int o = 1; o < 64; o <<= 1) sm += __shfl_xor(sm, o);
            attn_t[l][h] = e / sm;
        }
    }
    __syncthreads();

    // ---- phase 3: w[h][m] = sum_j attn[h][j] * value[b,i,j,m]; thread owns m = t + {0,256,512}
    {
        float acc[NHEADS][3];
        #pragma unroll
        for (int h = 0; h < NHEADS; ++h) { acc[h][0] = 0.f; acc[h][1] = 0.f; acc[h][2] = 0.f; }
        const float* vb = value + kvbase + t;
        for (int j = 0; j < 64; ++j) {
            float4 q0 = *reinterpret_cast<const float4*>(&attn_t[j][0]);
            float4 q1 = *reinterpret_cast<const float4*>(&attn_t[j][4]);
            float4 q2 = *reinterpret_cast<const float4*>(&attn_t[j][8]);
            float av[NHEADS] = { q0.x, q0.y, q0.z, q0.w, q1.x, q1.y, q1.z, q1.w, q2.x, q2.y, q2.z, q2.w };
            float v0 = vb[(size_t)j * DMODEL];
            float v1 = vb[(size_t)j * DMODEL + 256];
            float v2 = vb[(size_t)j * DMODEL + 512];
            #pragma unroll
            for (int h = 0; h < NHEADS; ++h) {
                acc[h][0] += av[h] * v0;
                acc[h][1] += av[h] * v1;
                acc[h][2] += av[h] * v2;
            }
        }
        #pragma unroll
        for (int h = 0; h < NHEADS; ++h)
            #pragma unroll
            for (int mm = 0; mm < 3; ++mm)
                w[(size_t)bi * BIW + h * DMODEL + t + mm * 256] = acc[h][mm];
    }
}

// ---------------------------------------------------------------------------
extern "C" void kernel_launch(void* const* d_in, const int* in_sizes, int n_in,
                              void* d_out, int out_size, void* d_ws, size_t ws_size,
                              hipStream_t stream) {
    const float* key   = (const float*)d_in[0];
    const float* value = (const float*)d_in[1];
    const float* query = (const float*)d_in[2];
    const float* mask  = (const float*)d_in[3];
    const float* Wk    = (const float*)d_in[4];
    const float* bk    = (const float*)d_in[5];
    const float* Wv    = (const float*)d_in[6];
    const float* bv    = (const float*)d_in[7];
    const float* Wq    = (const float*)d_in[8];
    const float* bq    = (const float*)d_in[9];
    const float* Wo    = (const float*)d_in[10];
    const float* bo    = (const float*)d_in[11];
    float* out = (float*)d_out;

    float* wsf    = (float*)d_ws;
    float* qp_ctx = wsf;                       // 512*768 floats (Qp, later reused as ctx)
    float* u_w    = wsf + (size_t)RTOT * DMODEL;        // 512*9216 floats (u, later reused as w)
    float* cvec   = u_w + (size_t)RTOT * BIW;           // 512*12 floats

    dim3 gridL(16, 12);

    // 1. Qp = (query @ Wq + bq) / sqrt(64)
    linear_tile<<<gridL, 256, 0, stream>>>(query, DMODEL, 0, Wq, bq, qp_ctx, DMODEL, 0.125f);
    // 2. u, c from Qp and Wk/bk
    qk_prep<<<dim3(32, 12), 256, 0, stream>>>(qp_ctx, Wk, bk, u_w, cvec);
    // 3. scores/softmax/w  (w overwrites u region; each block stages its own u slice first)
    attn_core<<<512, 256, 0, stream>>>(key, value, mask, u_w, cvec, u_w);
    // 4. ctx[r, h*64+d] = w[r,h,:] @ Wv[:, h*64+d] + bv   (ctx overwrites Qp region)
    linear_tile<<<gridL, 256, 0, stream>>>(u_w, BIW, DMODEL, Wv, bv, qp_ctx, DMODEL, 1.0f);
    // 5. out = ctx @ Wo + bo
    linear_tile<<<gridL, 256, 0, stream>>>(qp_ctx, DMODEL, 0, Wo, bo, out, DMODEL, 1.0f);
}